// Round 3
// baseline (1112.970 us; speedup 1.0000x reference)
//
#include <hip/hip_runtime.h>

// ---------------------------------------------------------------------------
// GAT fraud detector, round 3:
//  - single-pass softmax aggregation (no max pass; exp clamp — range-safe)
//  - sd (attention coeffs) fused into GEMM epilogue
//  - parallel 3-kernel scan for CSR
//  - BN/pool via per-block partials (no atomics, no memsets)
// ---------------------------------------------------------------------------

typedef unsigned int uint;
typedef unsigned short ushort;

#define NEG_SLOPE 0.2f
#define BN_EPS 1e-5f

__device__ __forceinline__ float bf2f(uint u) { return __uint_as_float(u << 16); }
__device__ __forceinline__ ushort f2bf(float f) {
    uint u = __float_as_uint(f);
    u += 0x7fff + ((u >> 16) & 1);   // round-nearest-even
    return (ushort)(u >> 16);
}
__device__ __forceinline__ float lrelu(float x) { return x > 0.f ? x : NEG_SLOPE * x; }

// ---------------- CSR construction ----------------

__global__ void hist_kernel(const int* __restrict__ ei, int* __restrict__ deg, int E) {
    int e = blockIdx.x * blockDim.x + threadIdx.x;
    if (e < E) atomicAdd(&deg[ei[E + e]], 1);
}

// block-local exclusive scan of deg into offsets; block sums to bsum
__global__ void scan_part(const int* __restrict__ deg, int* __restrict__ offsets,
                          int* __restrict__ bsum, int N) {
    __shared__ int sh[256];
    int t = threadIdx.x;
    int base = blockIdx.x * 1024 + t * 4;
    int v0 = (base + 0 < N) ? deg[base + 0] : 0;
    int v1 = (base + 1 < N) ? deg[base + 1] : 0;
    int v2 = (base + 2 < N) ? deg[base + 2] : 0;
    int v3 = (base + 3 < N) ? deg[base + 3] : 0;
    int s = v0 + v1 + v2 + v3;
    sh[t] = s;
    __syncthreads();
    for (int off = 1; off < 256; off <<= 1) {
        int y = (t >= off) ? sh[t - off] : 0;
        __syncthreads();
        sh[t] += y;
        __syncthreads();
    }
    int p = sh[t] - s;   // exclusive prefix for this thread's 4 elems
    if (base + 0 < N) offsets[base + 0] = p;
    p += v0;
    if (base + 1 < N) offsets[base + 1] = p;
    p += v1;
    if (base + 2 < N) offsets[base + 2] = p;
    p += v2;
    if (base + 3 < N) offsets[base + 3] = p;
    if (t == 255) bsum[blockIdx.x] = sh[255];
}

__global__ void scan_top(const int* __restrict__ bsum, int* __restrict__ bexcl,
                         int nb, int* __restrict__ offsets, int N) {
    if (threadIdx.x == 0) {
        int run = 0;
        for (int b = 0; b < nb; ++b) { bexcl[b] = run; run += bsum[b]; }
        offsets[N] = run;
    }
}

__global__ void scan_add(int* __restrict__ offsets, int* __restrict__ cursor,
                         const int* __restrict__ bexcl, int N) {
    int add = bexcl[blockIdx.x];
    int base = blockIdx.x * 1024 + threadIdx.x * 4;
#pragma unroll
    for (int k = 0; k < 4; ++k) {
        int i = base + k;
        if (i < N) { int v = offsets[i] + add; offsets[i] = v; cursor[i] = v; }
    }
}

__global__ void scatter_kernel(const int* __restrict__ ei, int* __restrict__ cursor,
                               int* __restrict__ srcs, int E) {
    int e = blockIdx.x * blockDim.x + threadIdx.x;
    if (e < E) {
        int s = ei[e];
        int d = ei[E + e];
        int p = atomicAdd(&cursor[d], 1);
        srcs[p] = s;
    }
}

// ---------------- conversions ----------------

__global__ void cvt_x_kernel(const float* __restrict__ x, ushort* __restrict__ xb,
                             int total_real, int total_pad) {
    int i = blockIdx.x * blockDim.x + threadIdx.x;
    if (i < total_pad) xb[i] = (i < total_real) ? f2bf(x[i]) : (ushort)0;
}

// all three weight transposes in one kernel: Wt[n*K+k] = bf16(W[k*F+n])
__global__ void transpose_all_kernel(const float* __restrict__ W0, ushort* __restrict__ w0t,
                                     const float* __restrict__ W1, ushort* __restrict__ w1t,
                                     const float* __restrict__ W2, ushort* __restrict__ w2t) {
    int i = blockIdx.x * blockDim.x + threadIdx.x;
    if (i < 32768) {                       // W0: K=128,F=256
        int n = i / 128, k = i - n * 128;
        w0t[i] = f2bf(W0[(size_t)k * 256 + n]);
    } else if (i < 32768 + 65536) {        // W1: K=256,F=256
        int j = i - 32768;
        int n = j / 256, k = j - n * 256;
        w1t[j] = f2bf(W1[(size_t)k * 256 + n]);
    } else if (i < 32768 + 65536 + 16384) { // W2: K=256,F=64
        int j = i - 32768 - 65536;
        int n = j / 256, k = j - n * 256;
        w2t[j] = f2bf(W2[(size_t)k * 64 + n]);
    }
}

// ---------------- bf16 MFMA GEMM with fused sd epilogue ----------------
// C[M,Nn] = A[M,K] @ Bt[Nn,K]^T ; also sv[row,H], dv[row,H] = (h*a).sum per head.
// BM=128 x BN per block, 256 threads (4 waves), BK=32, global_load_lds staging.

typedef __attribute__((ext_vector_type(8))) short bf16x8;
typedef __attribute__((ext_vector_type(4))) float floatx4;

template <int BN, int H>
__launch_bounds__(256)
__global__ void mfma_gemm_bt(const ushort* __restrict__ A, const ushort* __restrict__ Bt,
                             ushort* __restrict__ C, const float* __restrict__ asrc,
                             const float* __restrict__ adst, float* __restrict__ sv,
                             float* __restrict__ dv, int K, int Nn) {
    constexpr int WCOLS = (BN == 128) ? 2 : 1;
    constexpr int WROWS = 4 / WCOLS;
    constexpr int MT = 128 / (WROWS * 16);
    constexpr int NT = BN / (WCOLS * 16);
    constexpr int BCALLS = (BN * 32 * 2) / 4096;

    __shared__ ushort As[128 * 32];
    __shared__ ushort Bs[BN * 32];

    int t = threadIdx.x;
    int w = t >> 6, l = t & 63;
    int row0 = blockIdx.x * 128;
    int col0 = blockIdx.y * BN;
    int wr = (w / WCOLS) * (MT * 16);
    int wc = (w % WCOLS) * (NT * 16);

    floatx4 acc[MT][NT];
#pragma unroll
    for (int mi = 0; mi < MT; ++mi)
#pragma unroll
        for (int ni = 0; ni < NT; ++ni)
#pragma unroll
            for (int r = 0; r < 4; ++r) acc[mi][ni][r] = 0.f;

    int mrow = l & 15;
    int kc = (l >> 4) * 8;

    for (int kt = 0; kt < K; kt += 32) {
#pragma unroll
        for (int c = 0; c < 2; ++c) {
            int idx = c * 256 + t;
            const ushort* gp = A + (size_t)(row0 + (idx >> 2)) * K + kt + (idx & 3) * 8;
            __builtin_amdgcn_global_load_lds(
                (const __attribute__((address_space(1))) void*)gp,
                (__attribute__((address_space(3))) void*)(As + (idx & ~63) * 8),
                16, 0, 0);
        }
#pragma unroll
        for (int c = 0; c < BCALLS; ++c) {
            int idx = c * 256 + t;
            const ushort* gp = Bt + (size_t)(col0 + (idx >> 2)) * K + kt + (idx & 3) * 8;
            __builtin_amdgcn_global_load_lds(
                (const __attribute__((address_space(1))) void*)gp,
                (__attribute__((address_space(3))) void*)(Bs + (idx & ~63) * 8),
                16, 0, 0);
        }
        __syncthreads();

        bf16x8 af[MT], bfr[NT];
#pragma unroll
        for (int mi = 0; mi < MT; ++mi)
            af[mi] = *(const bf16x8*)&As[(wr + mi * 16 + mrow) * 32 + kc];
#pragma unroll
        for (int ni = 0; ni < NT; ++ni)
            bfr[ni] = *(const bf16x8*)&Bs[(wc + ni * 16 + mrow) * 32 + kc];
#pragma unroll
        for (int mi = 0; mi < MT; ++mi)
#pragma unroll
            for (int ni = 0; ni < NT; ++ni)
                acc[mi][ni] = __builtin_amdgcn_mfma_f32_16x16x32_bf16(
                    af[mi], bfr[ni], acc[mi][ni], 0, 0, 0);
        __syncthreads();
    }

    // C store (C/D layout: col=lane&15, row=(lane>>4)*4+reg)
#pragma unroll
    for (int mi = 0; mi < MT; ++mi) {
        int rbase = row0 + wr + mi * 16 + (l >> 4) * 4;
#pragma unroll
        for (int ni = 0; ni < NT; ++ni) {
            int col = col0 + wc + ni * 16 + (l & 15);
#pragma unroll
            for (int r = 0; r < 4; ++r)
                C[(size_t)(rbase + r) * Nn + col] = f2bf(acc[mi][ni][r]);
        }
    }

    // fused sd: this wave's NT*16 cols lie in exactly one head (64 cols).
    float av[NT], bv[NT];
#pragma unroll
    for (int ni = 0; ni < NT; ++ni) {
        int ch = col0 + wc + ni * 16 + (l & 15);
        av[ni] = asrc[ch];
        bv[ni] = adst[ch];
    }
    int gh = (col0 + wc) >> 6;   // global head for this wave
#pragma unroll
    for (int mi = 0; mi < MT; ++mi) {
#pragma unroll
        for (int r = 0; r < 4; ++r) {
            float s = 0.f, d = 0.f;
#pragma unroll
            for (int ni = 0; ni < NT; ++ni) {
                float hv = acc[mi][ni][r];
                s += hv * av[ni];
                d += hv * bv[ni];
            }
#pragma unroll
            for (int m = 8; m >= 1; m >>= 1) {
                s += __shfl_xor(s, m);
                d += __shfl_xor(d, m);
            }
            if ((l & 15) == 0) {
                int row = row0 + wr + mi * 16 + (l >> 4) * 4 + r;
                sv[row * H + gh] = s;
                dv[row * H + gh] = d;
            }
        }
    }
}

// ---------------- single-pass softmax aggregation ----------------
// exp without max-subtraction: e = lrelu(s+d), |e| <~ 20 in this net; clamp 60
// guards overflow. Ratios are exact regardless of shift.

__launch_bounds__(128)
__global__ void agg4_kernel(const ushort* __restrict__ hb, const float* __restrict__ sv,
                            const float* __restrict__ dv, const int* __restrict__ offsets,
                            const int* __restrict__ srcs, const float* __restrict__ bias,
                            ushort* __restrict__ zb, int N) {
    int i = blockIdx.x;
    int t = threadIdx.x, g = t >> 5;
    int beg = offsets[i], end = offsets[i + 1];

    float d_i = dv[i * 4 + g];
    float wself = __expf(fminf(lrelu(sv[i * 4 + g] + d_i), 60.f));

    uint p = *(const uint*)&hb[(size_t)i * 256 + 2 * t];
    float ax = wself * bf2f(p & 0xffffu);
    float ay = wself * bf2f(p >> 16);
    float den = wself;

    int j = beg;
    int srcn_next = (j < end) ? srcs[j] : 0;
    for (; j < end;) {
        int srcn = srcn_next;
        float sval = sv[srcn * 4 + g];
        uint q = *(const uint*)&hb[(size_t)srcn * 256 + 2 * t];
        ++j;
        if (j < end) srcn_next = srcs[j];
        float wgt = __expf(fminf(lrelu(sval + d_i), 60.f));
        ax += wgt * bf2f(q & 0xffffu);
        ay += wgt * bf2f(q >> 16);
        den += wgt;
    }
    float rden = 1.f / (den + 1e-16f);
    ax = ax * rden + bias[2 * t];
    ay = ay * rden + bias[2 * t + 1];
    *(uint*)&zb[(size_t)i * 256 + 2 * t] = (uint)f2bf(ax) | ((uint)f2bf(ay) << 16);
}

__launch_bounds__(64)
__global__ void agg1_kernel(const ushort* __restrict__ hb, const float* __restrict__ sv,
                            const float* __restrict__ dv, const int* __restrict__ offsets,
                            const int* __restrict__ srcs, const float* __restrict__ bias,
                            ushort* __restrict__ zb, int N) {
    int i = blockIdx.x;
    int lane = threadIdx.x;
    int beg = offsets[i], end = offsets[i + 1];

    float d_i = dv[i];
    float wself = __expf(fminf(lrelu(sv[i] + d_i), 60.f));
    float acc = wself * bf2f(hb[(size_t)i * 64 + lane]);
    float den = wself;

    int j = beg;
    int srcn_next = (j < end) ? srcs[j] : 0;
    for (; j < end;) {
        int srcn = srcn_next;
        float sval = sv[srcn];
        float hv = bf2f(hb[(size_t)srcn * 64 + lane]);
        ++j;
        if (j < end) srcn_next = srcs[j];
        float wgt = __expf(fminf(lrelu(sval + d_i), 60.f));
        acc += wgt * hv;
        den += wgt;
    }
    zb[(size_t)i * 64 + lane] = f2bf(acc / (den + 1e-16f) + bias[lane]);
}

// ---------------- BatchNorm (partials, no atomics) ----------------

__global__ void bn_stats_kernel(const ushort* __restrict__ x, float* __restrict__ ps,
                                float* __restrict__ pq, int N, int F) {
    int t = threadIdx.x;
    int col = t % F;
    int rg = t / F;
    int RG = 256 / F;
    int rows_per = (N + gridDim.x - 1) / gridDim.x;
    int r0 = blockIdx.x * rows_per;
    int r1 = min(N, r0 + rows_per);
    float s = 0.f, q = 0.f;
    for (int r = r0 + rg; r < r1; r += RG) {
        float v = bf2f(x[(size_t)r * F + col]);
        s += v; q += v * v;
    }
    __shared__ float ls[256], lq[256];
    ls[t] = s; lq[t] = q;
    __syncthreads();
    if (t < F) {
        for (int g = 1; g < RG; ++g) { s += ls[t + g * F]; q += lq[t + g * F]; }
        ps[blockIdx.x * F + t] = s;
        pq[blockIdx.x * F + t] = q;
    }
}

__global__ void bn_final_kernel(const float* __restrict__ ps, const float* __restrict__ pq,
                                const float* __restrict__ g, const float* __restrict__ be,
                                float* __restrict__ scale, float* __restrict__ shift,
                                int N, int F, int NB) {
    int t = threadIdx.x;
    if (t < F) {
        float s = 0.f, q = 0.f;
        for (int b = 0; b < NB; ++b) { s += ps[b * F + t]; q += pq[b * F + t]; }
        float mean = s / (float)N;
        float var = q / (float)N - mean * mean;
        float sc = g[t] * rsqrtf(var + BN_EPS);
        scale[t] = sc;
        shift[t] = be[t] - sc * mean;
    }
}

__global__ void bn_apply_kernel(uint* __restrict__ x, const float* __restrict__ scale,
                                const float* __restrict__ shift, int totalPairs, int Fmask) {
    int i = blockIdx.x * blockDim.x + threadIdx.x;
    if (i < totalPairs) {
        uint p = x[i];
        int c0 = (2 * i) & Fmask;
        float v0 = fmaxf(bf2f(p & 0xffffu) * scale[c0] + shift[c0], 0.f);
        float v1 = fmaxf(bf2f(p >> 16) * scale[c0 + 1] + shift[c0 + 1], 0.f);
        x[i] = (uint)f2bf(v0) | ((uint)f2bf(v1) << 16);
    }
}

// ---------------- pooling (with fused BN+ReLU) + classifier ----------------

__global__ void pool_kernel(const ushort* __restrict__ y, const float* __restrict__ scale,
                            const float* __restrict__ shift, float* __restrict__ psum,
                            float* __restrict__ pmax, int N) {
    const int F = 64;
    int t = threadIdx.x;
    int col = t & 63;
    int rg = t >> 6;
    const int RG = 4;
    int rows_per = (N + gridDim.x - 1) / gridDim.x;
    int r0 = blockIdx.x * rows_per;
    int r1 = min(N, r0 + rows_per);
    float sc = scale[col], sh = shift[col];
    float s = 0.f, m = 0.f;   // post-ReLU values >= 0
    for (int r = r0 + rg; r < r1; r += RG) {
        float v = fmaxf(bf2f(y[(size_t)r * F + col]) * sc + sh, 0.f);
        s += v; m = fmaxf(m, v);
    }
    __shared__ float ls[256], lm[256];
    ls[t] = s; lm[t] = m;
    __syncthreads();
    if (t < F) {
        for (int g = 1; g < RG; ++g) { s += ls[t + g * F]; m = fmaxf(m, lm[t + g * F]); }
        psum[blockIdx.x * F + t] = s;
        pmax[blockIdx.x * F + t] = m;
    }
}

__global__ void classify_kernel(const float* __restrict__ psum, const float* __restrict__ pmax,
                                const float* __restrict__ Wc1, const float* __restrict__ bc1,
                                const float* __restrict__ Wc2, const float* __restrict__ bc2,
                                float* __restrict__ out, int N, int NB) {
    __shared__ float pooled[128];
    __shared__ float z[64];
    int t = threadIdx.x;   // 128 threads
    if (t < 64) {
        float s = 0.f;
        for (int b = 0; b < NB; ++b) s += psum[b * 64 + t];
        pooled[t] = s / (float)N;
    } else {
        int c = t - 64;
        float m = 0.f;
        for (int b = 0; b < NB; ++b) m = fmaxf(m, pmax[b * 64 + c]);
        pooled[t] = m;
    }
    __syncthreads();
    if (t < 64) {
        float a = bc1[t];
        for (int k = 0; k < 128; ++k) a += pooled[k] * Wc1[k * 64 + t];
        z[t] = a > 0.f ? a : 0.f;
    }
    __syncthreads();
    if (t < 2) {
        float a = bc2[t];
        for (int j = 0; j < 64; ++j) a += z[j] * Wc2[j * 2 + t];
        out[t] = a;
    }
}

// ---------------- driver ----------------

extern "C" void kernel_launch(void* const* d_in, const int* in_sizes, int n_in,
                              void* d_out, int out_size, void* d_ws, size_t ws_size,
                              hipStream_t stream) {
    const float* x   = (const float*)d_in[0];
    const int*   ei  = (const int*)d_in[1];
    const float* W0  = (const float*)d_in[2];  const float* b0  = (const float*)d_in[3];
    const float* as0 = (const float*)d_in[4];  const float* ad0 = (const float*)d_in[5];
    const float* g0  = (const float*)d_in[6];  const float* be0 = (const float*)d_in[7];
    const float* W1  = (const float*)d_in[8];  const float* b1  = (const float*)d_in[9];
    const float* as1 = (const float*)d_in[10]; const float* ad1 = (const float*)d_in[11];
    const float* g1  = (const float*)d_in[12]; const float* be1 = (const float*)d_in[13];
    const float* W2  = (const float*)d_in[14]; const float* b2  = (const float*)d_in[15];
    const float* as2 = (const float*)d_in[16]; const float* ad2 = (const float*)d_in[17];
    const float* g2  = (const float*)d_in[18]; const float* be2 = (const float*)d_in[19];
    const float* Wc1 = (const float*)d_in[20]; const float* bc1 = (const float*)d_in[21];
    const float* Wc2 = (const float*)d_in[22]; const float* bc2 = (const float*)d_in[23];
    float* out = (float*)d_out;

    const int N = in_sizes[0] / 128;            // 50000
    const int E = in_sizes[1] / 2;              // 800000
    const int Mpad = ((N + 127) / 128) * 128;   // 50048
    const int NB_SCAN = (N + 1023) / 1024;      // 49
    const int NB_BN = 64;

    char* ws = (char*)d_ws;
    size_t o = 0;
    auto alloc = [&](size_t bytes) -> void* {
        void* p = ws + o;
        o = (o + bytes + 255) & ~(size_t)255;
        return p;
    };
    int*    deg     = (int*)alloc((size_t)N * 4);
    int*    offsets = (int*)alloc((size_t)(N + 1) * 4);
    int*    cursor  = (int*)alloc((size_t)N * 4);
    int*    srcs    = (int*)alloc((size_t)E * 4);
    int*    bsum    = (int*)alloc((size_t)NB_SCAN * 4);
    int*    bexcl   = (int*)alloc((size_t)NB_SCAN * 4);
    ushort* xb      = (ushort*)alloc((size_t)Mpad * 128 * 2);
    ushort* w0t     = (ushort*)alloc((size_t)256 * 128 * 2);
    ushort* w1t     = (ushort*)alloc((size_t)256 * 256 * 2);
    ushort* w2t     = (ushort*)alloc((size_t)64 * 256 * 2);
    ushort* hb      = (ushort*)alloc((size_t)Mpad * 256 * 2);
    ushort* zb      = (ushort*)alloc((size_t)Mpad * 256 * 2);
    float*  sv      = (float*)alloc((size_t)Mpad * 4 * 4);
    float*  dv      = (float*)alloc((size_t)Mpad * 4 * 4);
    float*  ps      = (float*)alloc((size_t)NB_BN * 256 * 4);
    float*  pq      = (float*)alloc((size_t)NB_BN * 256 * 4);
    float*  scale   = (float*)alloc(256 * 4);
    float*  shift   = (float*)alloc(256 * 4);
    float*  psum    = (float*)alloc((size_t)NB_BN * 64 * 4);
    float*  pmax    = (float*)alloc((size_t)NB_BN * 64 * 4);

    // ---- CSR by destination ----
    hipMemsetAsync(deg, 0, (size_t)N * 4, stream);
    int eb = (E + 255) / 256;
    hist_kernel<<<eb, 256, 0, stream>>>(ei, deg, E);
    scan_part<<<NB_SCAN, 256, 0, stream>>>(deg, offsets, bsum, N);
    scan_top<<<1, 64, 0, stream>>>(bsum, bexcl, NB_SCAN, offsets, N);
    scan_add<<<NB_SCAN, 256, 0, stream>>>(offsets, cursor, bexcl, N);
    scatter_kernel<<<eb, 256, 0, stream>>>(ei, cursor, srcs, E);

    // ---- conversions ----
    cvt_x_kernel<<<(Mpad * 128 + 255) / 256, 256, 0, stream>>>(x, xb, N * 128, Mpad * 128);
    transpose_all_kernel<<<(32768 + 65536 + 16384 + 255) / 256, 256, 0, stream>>>(
        W0, w0t, W1, w1t, W2, w2t);

    auto bn_block = [&](int F, const float* gamma, const float* beta, bool apply) {
        bn_stats_kernel<<<NB_BN, 256, 0, stream>>>(zb, ps, pq, N, F);
        bn_final_kernel<<<1, F, 0, stream>>>(ps, pq, gamma, beta, scale, shift, N, F, NB_BN);
        if (apply) {
            int pairs = N * F / 2;
            bn_apply_kernel<<<(pairs + 255) / 256, 256, 0, stream>>>((uint*)zb, scale, shift,
                                                                     pairs, F - 1);
        }
    };

    // ---- layer 0: xb[Mpad,128] -> hb[Mpad,256] (+sv,dv) -> zb ----
    {
        dim3 gg(Mpad / 128, 2);
        mfma_gemm_bt<128, 4><<<gg, 256, 0, stream>>>(xb, w0t, hb, as0, ad0, sv, dv, 128, 256);
        agg4_kernel<<<N, 128, 0, stream>>>(hb, sv, dv, offsets, srcs, b0, zb, N);
        bn_block(256, g0, be0, true);
    }
    // ---- layer 1 ----
    {
        dim3 gg(Mpad / 128, 2);
        mfma_gemm_bt<128, 4><<<gg, 256, 0, stream>>>(zb, w1t, hb, as1, ad1, sv, dv, 256, 256);
        agg4_kernel<<<N, 128, 0, stream>>>(hb, sv, dv, offsets, srcs, b1, zb, N);
        bn_block(256, g1, be1, true);
    }
    // ---- layer 2 (1 head, F=64); BN-apply fused into pool ----
    {
        dim3 gg(Mpad / 128, 1);
        mfma_gemm_bt<64, 1><<<gg, 256, 0, stream>>>(zb, w2t, hb, as2, ad2, sv, dv, 256, 64);
        agg1_kernel<<<N, 64, 0, stream>>>(hb, sv, dv, offsets, srcs, b2, zb, N);
        bn_block(64, g2, be2, false);
    }

    // ---- pooling (BN+ReLU fused) + classifier ----
    pool_kernel<<<NB_BN, 256, 0, stream>>>(zb, scale, shift, psum, pmax, N);
    classify_kernel<<<1, 128, 0, stream>>>(psum, pmax, Wc1, bc1, Wc2, bc2, out, N, NB_BN);
}

// Round 4
// 686.619 us; speedup vs baseline: 1.6209x; 1.6209x over previous
//
#include <hip/hip_runtime.h>

// ---------------------------------------------------------------------------
// GAT fraud detector, round 4:
//  - round 3 pipeline (single-pass agg, fused sd in GEMM epilogue, parallel scan)
//  - bn_stats / pool rewritten: uint4 (8x bf16) coalesced grid-stride loads,
//    256-block grids, register accumulators + LDS-atomic flush.
//    (round-3 versions were 64-block scalar-load latency disasters: 208 us @ 62 GB/s)
// ---------------------------------------------------------------------------

typedef unsigned int uint;
typedef unsigned short ushort;

#define NEG_SLOPE 0.2f
#define BN_EPS 1e-5f
#define NB_RED 256   // blocks for BN-stats / pool partial reductions

__device__ __forceinline__ float bf2f(uint u) { return __uint_as_float(u << 16); }
__device__ __forceinline__ ushort f2bf(float f) {
    uint u = __float_as_uint(f);
    u += 0x7fff + ((u >> 16) & 1);   // round-nearest-even
    return (ushort)(u >> 16);
}
__device__ __forceinline__ float lrelu(float x) { return x > 0.f ? x : NEG_SLOPE * x; }

// ---------------- CSR construction ----------------

__global__ void hist_kernel(const int* __restrict__ ei, int* __restrict__ deg, int E) {
    int e = blockIdx.x * blockDim.x + threadIdx.x;
    if (e < E) atomicAdd(&deg[ei[E + e]], 1);
}

__global__ void scan_part(const int* __restrict__ deg, int* __restrict__ offsets,
                          int* __restrict__ bsum, int N) {
    __shared__ int sh[256];
    int t = threadIdx.x;
    int base = blockIdx.x * 1024 + t * 4;
    int v0 = (base + 0 < N) ? deg[base + 0] : 0;
    int v1 = (base + 1 < N) ? deg[base + 1] : 0;
    int v2 = (base + 2 < N) ? deg[base + 2] : 0;
    int v3 = (base + 3 < N) ? deg[base + 3] : 0;
    int s = v0 + v1 + v2 + v3;
    sh[t] = s;
    __syncthreads();
    for (int off = 1; off < 256; off <<= 1) {
        int y = (t >= off) ? sh[t - off] : 0;
        __syncthreads();
        sh[t] += y;
        __syncthreads();
    }
    int p = sh[t] - s;
    if (base + 0 < N) offsets[base + 0] = p;
    p += v0;
    if (base + 1 < N) offsets[base + 1] = p;
    p += v1;
    if (base + 2 < N) offsets[base + 2] = p;
    p += v2;
    if (base + 3 < N) offsets[base + 3] = p;
    if (t == 255) bsum[blockIdx.x] = sh[255];
}

__global__ void scan_top(const int* __restrict__ bsum, int* __restrict__ bexcl,
                         int nb, int* __restrict__ offsets, int N) {
    if (threadIdx.x == 0) {
        int run = 0;
        for (int b = 0; b < nb; ++b) { bexcl[b] = run; run += bsum[b]; }
        offsets[N] = run;
    }
}

__global__ void scan_add(int* __restrict__ offsets, int* __restrict__ cursor,
                         const int* __restrict__ bexcl, int N) {
    int add = bexcl[blockIdx.x];
    int base = blockIdx.x * 1024 + threadIdx.x * 4;
#pragma unroll
    for (int k = 0; k < 4; ++k) {
        int i = base + k;
        if (i < N) { int v = offsets[i] + add; offsets[i] = v; cursor[i] = v; }
    }
}

__global__ void scatter_kernel(const int* __restrict__ ei, int* __restrict__ cursor,
                               int* __restrict__ srcs, int E) {
    int e = blockIdx.x * blockDim.x + threadIdx.x;
    if (e < E) {
        int s = ei[e];
        int d = ei[E + e];
        int p = atomicAdd(&cursor[d], 1);
        srcs[p] = s;
    }
}

// ---------------- conversions ----------------

__global__ void cvt_x_kernel(const float* __restrict__ x, ushort* __restrict__ xb,
                             int total_real, int total_pad) {
    int i = blockIdx.x * blockDim.x + threadIdx.x;
    if (i < total_pad) xb[i] = (i < total_real) ? f2bf(x[i]) : (ushort)0;
}

__global__ void transpose_all_kernel(const float* __restrict__ W0, ushort* __restrict__ w0t,
                                     const float* __restrict__ W1, ushort* __restrict__ w1t,
                                     const float* __restrict__ W2, ushort* __restrict__ w2t) {
    int i = blockIdx.x * blockDim.x + threadIdx.x;
    if (i < 32768) {                       // W0: K=128,F=256
        int n = i / 128, k = i - n * 128;
        w0t[i] = f2bf(W0[(size_t)k * 256 + n]);
    } else if (i < 32768 + 65536) {        // W1: K=256,F=256
        int j = i - 32768;
        int n = j / 256, k = j - n * 256;
        w1t[j] = f2bf(W1[(size_t)k * 256 + n]);
    } else if (i < 32768 + 65536 + 16384) { // W2: K=256,F=64
        int j = i - 32768 - 65536;
        int n = j / 256, k = j - n * 256;
        w2t[j] = f2bf(W2[(size_t)k * 64 + n]);
    }
}

// ---------------- bf16 MFMA GEMM with fused sd epilogue ----------------

typedef __attribute__((ext_vector_type(8))) short bf16x8;
typedef __attribute__((ext_vector_type(4))) float floatx4;

template <int BN, int H>
__launch_bounds__(256)
__global__ void mfma_gemm_bt(const ushort* __restrict__ A, const ushort* __restrict__ Bt,
                             ushort* __restrict__ C, const float* __restrict__ asrc,
                             const float* __restrict__ adst, float* __restrict__ sv,
                             float* __restrict__ dv, int K, int Nn) {
    constexpr int WCOLS = (BN == 128) ? 2 : 1;
    constexpr int WROWS = 4 / WCOLS;
    constexpr int MT = 128 / (WROWS * 16);
    constexpr int NT = BN / (WCOLS * 16);
    constexpr int BCALLS = (BN * 32 * 2) / 4096;

    __shared__ ushort As[128 * 32];
    __shared__ ushort Bs[BN * 32];

    int t = threadIdx.x;
    int w = t >> 6, l = t & 63;
    int row0 = blockIdx.x * 128;
    int col0 = blockIdx.y * BN;
    int wr = (w / WCOLS) * (MT * 16);
    int wc = (w % WCOLS) * (NT * 16);

    floatx4 acc[MT][NT];
#pragma unroll
    for (int mi = 0; mi < MT; ++mi)
#pragma unroll
        for (int ni = 0; ni < NT; ++ni)
#pragma unroll
            for (int r = 0; r < 4; ++r) acc[mi][ni][r] = 0.f;

    int mrow = l & 15;
    int kc = (l >> 4) * 8;

    for (int kt = 0; kt < K; kt += 32) {
#pragma unroll
        for (int c = 0; c < 2; ++c) {
            int idx = c * 256 + t;
            const ushort* gp = A + (size_t)(row0 + (idx >> 2)) * K + kt + (idx & 3) * 8;
            __builtin_amdgcn_global_load_lds(
                (const __attribute__((address_space(1))) void*)gp,
                (__attribute__((address_space(3))) void*)(As + (idx & ~63) * 8),
                16, 0, 0);
        }
#pragma unroll
        for (int c = 0; c < BCALLS; ++c) {
            int idx = c * 256 + t;
            const ushort* gp = Bt + (size_t)(col0 + (idx >> 2)) * K + kt + (idx & 3) * 8;
            __builtin_amdgcn_global_load_lds(
                (const __attribute__((address_space(1))) void*)gp,
                (__attribute__((address_space(3))) void*)(Bs + (idx & ~63) * 8),
                16, 0, 0);
        }
        __syncthreads();

        bf16x8 af[MT], bfr[NT];
#pragma unroll
        for (int mi = 0; mi < MT; ++mi)
            af[mi] = *(const bf16x8*)&As[(wr + mi * 16 + mrow) * 32 + kc];
#pragma unroll
        for (int ni = 0; ni < NT; ++ni)
            bfr[ni] = *(const bf16x8*)&Bs[(wc + ni * 16 + mrow) * 32 + kc];
#pragma unroll
        for (int mi = 0; mi < MT; ++mi)
#pragma unroll
            for (int ni = 0; ni < NT; ++ni)
                acc[mi][ni] = __builtin_amdgcn_mfma_f32_16x16x32_bf16(
                    af[mi], bfr[ni], acc[mi][ni], 0, 0, 0);
        __syncthreads();
    }

    // C store (C/D layout: col=lane&15, row=(lane>>4)*4+reg)
#pragma unroll
    for (int mi = 0; mi < MT; ++mi) {
        int rbase = row0 + wr + mi * 16 + (l >> 4) * 4;
#pragma unroll
        for (int ni = 0; ni < NT; ++ni) {
            int col = col0 + wc + ni * 16 + (l & 15);
#pragma unroll
            for (int r = 0; r < 4; ++r)
                C[(size_t)(rbase + r) * Nn + col] = f2bf(acc[mi][ni][r]);
        }
    }

    // fused sd: this wave's NT*16 cols lie in exactly one head (64 cols).
    float av[NT], bv[NT];
#pragma unroll
    for (int ni = 0; ni < NT; ++ni) {
        int ch = col0 + wc + ni * 16 + (l & 15);
        av[ni] = asrc[ch];
        bv[ni] = adst[ch];
    }
    int gh = (col0 + wc) >> 6;
#pragma unroll
    for (int mi = 0; mi < MT; ++mi) {
#pragma unroll
        for (int r = 0; r < 4; ++r) {
            float s = 0.f, d = 0.f;
#pragma unroll
            for (int ni = 0; ni < NT; ++ni) {
                float hv = acc[mi][ni][r];
                s += hv * av[ni];
                d += hv * bv[ni];
            }
#pragma unroll
            for (int m = 8; m >= 1; m >>= 1) {
                s += __shfl_xor(s, m);
                d += __shfl_xor(d, m);
            }
            if ((l & 15) == 0) {
                int row = row0 + wr + mi * 16 + (l >> 4) * 4 + r;
                sv[row * H + gh] = s;
                dv[row * H + gh] = d;
            }
        }
    }
}

// ---------------- single-pass softmax aggregation ----------------

__launch_bounds__(128)
__global__ void agg4_kernel(const ushort* __restrict__ hb, const float* __restrict__ sv,
                            const float* __restrict__ dv, const int* __restrict__ offsets,
                            const int* __restrict__ srcs, const float* __restrict__ bias,
                            ushort* __restrict__ zb, int N) {
    int i = blockIdx.x;
    int t = threadIdx.x, g = t >> 5;
    int beg = offsets[i], end = offsets[i + 1];

    float d_i = dv[i * 4 + g];
    float wself = __expf(fminf(lrelu(sv[i * 4 + g] + d_i), 60.f));

    uint p = *(const uint*)&hb[(size_t)i * 256 + 2 * t];
    float ax = wself * bf2f(p & 0xffffu);
    float ay = wself * bf2f(p >> 16);
    float den = wself;

    int j = beg;
    int srcn_next = (j < end) ? srcs[j] : 0;
    for (; j < end;) {
        int srcn = srcn_next;
        float sval = sv[srcn * 4 + g];
        uint q = *(const uint*)&hb[(size_t)srcn * 256 + 2 * t];
        ++j;
        if (j < end) srcn_next = srcs[j];
        float wgt = __expf(fminf(lrelu(sval + d_i), 60.f));
        ax += wgt * bf2f(q & 0xffffu);
        ay += wgt * bf2f(q >> 16);
        den += wgt;
    }
    float rden = 1.f / (den + 1e-16f);
    ax = ax * rden + bias[2 * t];
    ay = ay * rden + bias[2 * t + 1];
    *(uint*)&zb[(size_t)i * 256 + 2 * t] = (uint)f2bf(ax) | ((uint)f2bf(ay) << 16);
}

__launch_bounds__(64)
__global__ void agg1_kernel(const ushort* __restrict__ hb, const float* __restrict__ sv,
                            const float* __restrict__ dv, const int* __restrict__ offsets,
                            const int* __restrict__ srcs, const float* __restrict__ bias,
                            ushort* __restrict__ zb, int N) {
    int i = blockIdx.x;
    int lane = threadIdx.x;
    int beg = offsets[i], end = offsets[i + 1];

    float d_i = dv[i];
    float wself = __expf(fminf(lrelu(sv[i] + d_i), 60.f));
    float acc = wself * bf2f(hb[(size_t)i * 64 + lane]);
    float den = wself;

    int j = beg;
    int srcn_next = (j < end) ? srcs[j] : 0;
    for (; j < end;) {
        int srcn = srcn_next;
        float sval = sv[srcn];
        float hv = bf2f(hb[(size_t)srcn * 64 + lane]);
        ++j;
        if (j < end) srcn_next = srcs[j];
        float wgt = __expf(fminf(lrelu(sval + d_i), 60.f));
        acc += wgt * hv;
        den += wgt;
    }
    zb[(size_t)i * 64 + lane] = f2bf(acc / (den + 1e-16f) + bias[lane]);
}

// ---------------- BatchNorm stats: vectorized grid-stride partials ----------------
// F columns; each thread owns a fixed column-octet (stride NB_RED*256 is a
// multiple of F/8), accumulates 8 cols in registers, flushes via LDS atomics.

template <int F>
__launch_bounds__(256)
__global__ void bn_stats_kernel(const ushort* __restrict__ x, float* __restrict__ ps,
                                float* __restrict__ pq, int N) {
    constexpr int OCT = F / 8;
    __shared__ float lds_s[F], lds_q[F];
    int t = threadIdx.x;
    if (t < F) { lds_s[t] = 0.f; lds_q[t] = 0.f; }
    __syncthreads();

    float s[8] = {}, q[8] = {};
    int total8 = N * F / 8;
    for (int idx = blockIdx.x * 256 + t; idx < total8; idx += NB_RED * 256) {
        uint4 v = ((const uint4*)x)[idx];
        uint pr[4] = {v.x, v.y, v.z, v.w};
#pragma unroll
        for (int k = 0; k < 4; ++k) {
            float a = bf2f(pr[k] & 0xffffu);
            float b = bf2f(pr[k] >> 16);
            s[2 * k] += a;     q[2 * k] += a * a;
            s[2 * k + 1] += b; q[2 * k + 1] += b * b;
        }
    }
    int co = t % OCT;
#pragma unroll
    for (int j = 0; j < 8; ++j) {
        atomicAdd(&lds_s[co * 8 + j], s[j]);
        atomicAdd(&lds_q[co * 8 + j], q[j]);
    }
    __syncthreads();
    if (t < F) {
        ps[blockIdx.x * F + t] = lds_s[t];
        pq[blockIdx.x * F + t] = lds_q[t];
    }
}

__global__ void bn_final_kernel(const float* __restrict__ ps, const float* __restrict__ pq,
                                const float* __restrict__ g, const float* __restrict__ be,
                                float* __restrict__ scale, float* __restrict__ shift,
                                int N, int F) {
    int t = threadIdx.x;
    if (t < F) {
        float s = 0.f, q = 0.f;
        for (int b = 0; b < NB_RED; ++b) { s += ps[b * F + t]; q += pq[b * F + t]; }
        float mean = s / (float)N;
        float var = q / (float)N - mean * mean;
        float sc = g[t] * rsqrtf(var + BN_EPS);
        scale[t] = sc;
        shift[t] = be[t] - sc * mean;
    }
}

__global__ void bn_apply_kernel(uint* __restrict__ x, const float* __restrict__ scale,
                                const float* __restrict__ shift, int totalPairs, int Fmask) {
    int i = blockIdx.x * blockDim.x + threadIdx.x;
    if (i < totalPairs) {
        uint p = x[i];
        int c0 = (2 * i) & Fmask;
        float v0 = fmaxf(bf2f(p & 0xffffu) * scale[c0] + shift[c0], 0.f);
        float v1 = fmaxf(bf2f(p >> 16) * scale[c0 + 1] + shift[c0 + 1], 0.f);
        x[i] = (uint)f2bf(v0) | ((uint)f2bf(v1) << 16);
    }
}

// ---------------- pooling (BN+ReLU fused, vectorized) ----------------
// F=64. Values post-ReLU are >= 0 so uint atomicMax is order-preserving.

__launch_bounds__(256)
__global__ void pool_kernel(const ushort* __restrict__ y, const float* __restrict__ scale,
                            const float* __restrict__ shift, float* __restrict__ psum,
                            float* __restrict__ pmax, int N) {
    constexpr int F = 64, OCT = 8;
    __shared__ float lds_s[F];
    __shared__ uint lds_m[F];
    int t = threadIdx.x;
    if (t < F) { lds_s[t] = 0.f; lds_m[t] = 0u; }
    __syncthreads();

    int co = t % OCT;
    float sc[8], sh[8];
#pragma unroll
    for (int j = 0; j < 8; ++j) { sc[j] = scale[co * 8 + j]; sh[j] = shift[co * 8 + j]; }

    float s[8] = {}, m[8] = {};
    int total8 = N * F / 8;
    for (int idx = blockIdx.x * 256 + t; idx < total8; idx += NB_RED * 256) {
        uint4 v = ((const uint4*)y)[idx];
        uint pr[4] = {v.x, v.y, v.z, v.w};
#pragma unroll
        for (int k = 0; k < 4; ++k) {
            float a = fmaxf(bf2f(pr[k] & 0xffffu) * sc[2 * k] + sh[2 * k], 0.f);
            float b = fmaxf(bf2f(pr[k] >> 16) * sc[2 * k + 1] + sh[2 * k + 1], 0.f);
            s[2 * k] += a;     m[2 * k] = fmaxf(m[2 * k], a);
            s[2 * k + 1] += b; m[2 * k + 1] = fmaxf(m[2 * k + 1], b);
        }
    }
#pragma unroll
    for (int j = 0; j < 8; ++j) {
        atomicAdd(&lds_s[co * 8 + j], s[j]);
        atomicMax(&lds_m[co * 8 + j], __float_as_uint(m[j]));
    }
    __syncthreads();
    if (t < F) {
        psum[blockIdx.x * F + t] = lds_s[t];
        pmax[blockIdx.x * F + t] = __uint_as_float(lds_m[t]);
    }
}

__global__ void classify_kernel(const float* __restrict__ psum, const float* __restrict__ pmax,
                                const float* __restrict__ Wc1, const float* __restrict__ bc1,
                                const float* __restrict__ Wc2, const float* __restrict__ bc2,
                                float* __restrict__ out, int N) {
    __shared__ float pooled[128];
    __shared__ float z[64];
    int t = threadIdx.x;   // 128 threads
    if (t < 64) {
        float s = 0.f;
        for (int b = 0; b < NB_RED; ++b) s += psum[b * 64 + t];
        pooled[t] = s / (float)N;
    } else {
        int c = t - 64;
        float m = 0.f;
        for (int b = 0; b < NB_RED; ++b) m = fmaxf(m, pmax[b * 64 + c]);
        pooled[t] = m;
    }
    __syncthreads();
    if (t < 64) {
        float a = bc1[t];
        for (int k = 0; k < 128; ++k) a += pooled[k] * Wc1[k * 64 + t];
        z[t] = a > 0.f ? a : 0.f;
    }
    __syncthreads();
    if (t < 2) {
        float a = bc2[t];
        for (int j = 0; j < 64; ++j) a += z[j] * Wc2[j * 2 + t];
        out[t] = a;
    }
}

// ---------------- driver ----------------

extern "C" void kernel_launch(void* const* d_in, const int* in_sizes, int n_in,
                              void* d_out, int out_size, void* d_ws, size_t ws_size,
                              hipStream_t stream) {
    const float* x   = (const float*)d_in[0];
    const int*   ei  = (const int*)d_in[1];
    const float* W0  = (const float*)d_in[2];  const float* b0  = (const float*)d_in[3];
    const float* as0 = (const float*)d_in[4];  const float* ad0 = (const float*)d_in[5];
    const float* g0  = (const float*)d_in[6];  const float* be0 = (const float*)d_in[7];
    const float* W1  = (const float*)d_in[8];  const float* b1  = (const float*)d_in[9];
    const float* as1 = (const float*)d_in[10]; const float* ad1 = (const float*)d_in[11];
    const float* g1  = (const float*)d_in[12]; const float* be1 = (const float*)d_in[13];
    const float* W2  = (const float*)d_in[14]; const float* b2  = (const float*)d_in[15];
    const float* as2 = (const float*)d_in[16]; const float* ad2 = (const float*)d_in[17];
    const float* g2  = (const float*)d_in[18]; const float* be2 = (const float*)d_in[19];
    const float* Wc1 = (const float*)d_in[20]; const float* bc1 = (const float*)d_in[21];
    const float* Wc2 = (const float*)d_in[22]; const float* bc2 = (const float*)d_in[23];
    float* out = (float*)d_out;

    const int N = in_sizes[0] / 128;            // 50000
    const int E = in_sizes[1] / 2;              // 800000
    const int Mpad = ((N + 127) / 128) * 128;   // 50048
    const int NB_SCAN = (N + 1023) / 1024;      // 49

    char* ws = (char*)d_ws;
    size_t o = 0;
    auto alloc = [&](size_t bytes) -> void* {
        void* p = ws + o;
        o = (o + bytes + 255) & ~(size_t)255;
        return p;
    };
    int*    deg     = (int*)alloc((size_t)N * 4);
    int*    offsets = (int*)alloc((size_t)(N + 1) * 4);
    int*    cursor  = (int*)alloc((size_t)N * 4);
    int*    srcs    = (int*)alloc((size_t)E * 4);
    int*    bsum    = (int*)alloc((size_t)NB_SCAN * 4);
    int*    bexcl   = (int*)alloc((size_t)NB_SCAN * 4);
    ushort* xb      = (ushort*)alloc((size_t)Mpad * 128 * 2);
    ushort* w0t     = (ushort*)alloc((size_t)256 * 128 * 2);
    ushort* w1t     = (ushort*)alloc((size_t)256 * 256 * 2);
    ushort* w2t     = (ushort*)alloc((size_t)64 * 256 * 2);
    ushort* hb      = (ushort*)alloc((size_t)Mpad * 256 * 2);
    ushort* zb      = (ushort*)alloc((size_t)Mpad * 256 * 2);
    float*  sv      = (float*)alloc((size_t)Mpad * 4 * 4);
    float*  dv      = (float*)alloc((size_t)Mpad * 4 * 4);
    float*  ps      = (float*)alloc((size_t)NB_RED * 256 * 4);
    float*  pq      = (float*)alloc((size_t)NB_RED * 256 * 4);
    float*  scale   = (float*)alloc(256 * 4);
    float*  shift   = (float*)alloc(256 * 4);
    float*  psum    = (float*)alloc((size_t)NB_RED * 64 * 4);
    float*  pmax    = (float*)alloc((size_t)NB_RED * 64 * 4);

    // ---- CSR by destination ----
    hipMemsetAsync(deg, 0, (size_t)N * 4, stream);
    int eb = (E + 255) / 256;
    hist_kernel<<<eb, 256, 0, stream>>>(ei, deg, E);
    scan_part<<<NB_SCAN, 256, 0, stream>>>(deg, offsets, bsum, N);
    scan_top<<<1, 64, 0, stream>>>(bsum, bexcl, NB_SCAN, offsets, N);
    scan_add<<<NB_SCAN, 256, 0, stream>>>(offsets, cursor, bexcl, N);
    scatter_kernel<<<eb, 256, 0, stream>>>(ei, cursor, srcs, E);

    // ---- conversions ----
    cvt_x_kernel<<<(Mpad * 128 + 255) / 256, 256, 0, stream>>>(x, xb, N * 128, Mpad * 128);
    transpose_all_kernel<<<(32768 + 65536 + 16384 + 255) / 256, 256, 0, stream>>>(
        W0, w0t, W1, w1t, W2, w2t);

    // ---- layer 0 ----
    {
        dim3 gg(Mpad / 128, 2);
        mfma_gemm_bt<128, 4><<<gg, 256, 0, stream>>>(xb, w0t, hb, as0, ad0, sv, dv, 128, 256);
        agg4_kernel<<<N, 128, 0, stream>>>(hb, sv, dv, offsets, srcs, b0, zb, N);
        bn_stats_kernel<256><<<NB_RED, 256, 0, stream>>>(zb, ps, pq, N);
        bn_final_kernel<<<1, 256, 0, stream>>>(ps, pq, g0, be0, scale, shift, N, 256);
        bn_apply_kernel<<<(N * 128 + 255) / 256, 256, 0, stream>>>((uint*)zb, scale, shift,
                                                                   N * 128, 255);
    }
    // ---- layer 1 ----
    {
        dim3 gg(Mpad / 128, 2);
        mfma_gemm_bt<128, 4><<<gg, 256, 0, stream>>>(zb, w1t, hb, as1, ad1, sv, dv, 256, 256);
        agg4_kernel<<<N, 128, 0, stream>>>(hb, sv, dv, offsets, srcs, b1, zb, N);
        bn_stats_kernel<256><<<NB_RED, 256, 0, stream>>>(zb, ps, pq, N);
        bn_final_kernel<<<1, 256, 0, stream>>>(ps, pq, g1, be1, scale, shift, N, 256);
        bn_apply_kernel<<<(N * 128 + 255) / 256, 256, 0, stream>>>((uint*)zb, scale, shift,
                                                                   N * 128, 255);
    }
    // ---- layer 2 (1 head, F=64); BN-apply fused into pool ----
    {
        dim3 gg(Mpad / 128, 1);
        mfma_gemm_bt<64, 1><<<gg, 256, 0, stream>>>(zb, w2t, hb, as2, ad2, sv, dv, 256, 64);
        agg1_kernel<<<N, 64, 0, stream>>>(hb, sv, dv, offsets, srcs, b2, zb, N);
        bn_stats_kernel<64><<<NB_RED, 256, 0, stream>>>(zb, ps, pq, N);
        bn_final_kernel<<<1, 64, 0, stream>>>(ps, pq, g2, be2, scale, shift, N, 64);
    }

    // ---- pooling (BN+ReLU fused) + classifier ----
    pool_kernel<<<NB_RED, 256, 0, stream>>>(zb, scale, shift, psum, pmax, N);
    classify_kernel<<<1, 128, 0, stream>>>(psum, pmax, Wc1, bc1, Wc2, bc2, out, N);
}

// Round 5
// 584.152 us; speedup vs baseline: 1.9053x; 1.1754x over previous
//
#include <hip/hip_runtime.h>

// ---------------------------------------------------------------------------
// GAT fraud detector, round 5:
//  - agg kernels restructured: 4 edge-groups per block, 16B/lane row loads
//    (1KB per wave instr), next-edge prefetch, exp amortized over 8 ch.
//    (round-4 agg4: serial edge loop, 4B/lane loads -> 107us @ 2.3TB/s, VALU 46%)
//  - prep fusion: cvt_x + weight transpose + hist in one kernel.
//  - rest identical to round 4 (MFMA GEMM + fused sd, parallel scan,
//    vectorized BN/pool partials).
// ---------------------------------------------------------------------------

typedef unsigned int uint;
typedef unsigned short ushort;

#define NEG_SLOPE 0.2f
#define BN_EPS 1e-5f
#define NB_RED 256   // blocks for BN-stats / pool partial reductions

__device__ __forceinline__ float bf2f(uint u) { return __uint_as_float(u << 16); }
__device__ __forceinline__ ushort f2bf(float f) {
    uint u = __float_as_uint(f);
    u += 0x7fff + ((u >> 16) & 1);   // round-nearest-even
    return (ushort)(u >> 16);
}
__device__ __forceinline__ float lrelu(float x) { return x > 0.f ? x : NEG_SLOPE * x; }

// ---------------- fused prep: cvt x -> bf16 (padded), transpose weights, histogram ----------------

__global__ void prep_kernel(const float* __restrict__ x, ushort* __restrict__ xb,
                            int total_real, int total_pad,
                            const float* __restrict__ W0, ushort* __restrict__ w0t,
                            const float* __restrict__ W1, ushort* __restrict__ w1t,
                            const float* __restrict__ W2, ushort* __restrict__ w2t,
                            const int* __restrict__ ei, int* __restrict__ deg, int E) {
    int i = blockIdx.x * blockDim.x + threadIdx.x;
    if (i < total_pad) {
        xb[i] = (i < total_real) ? f2bf(x[i]) : (ushort)0;
        return;
    }
    int j = i - total_pad;
    if (j < 32768) {                        // W0: K=128,F=256
        int n = j / 128, k = j - n * 128;
        w0t[j] = f2bf(W0[(size_t)k * 256 + n]);
        return;
    }
    j -= 32768;
    if (j < 65536) {                        // W1: K=256,F=256
        int n = j / 256, k = j - n * 256;
        w1t[j] = f2bf(W1[(size_t)k * 256 + n]);
        return;
    }
    j -= 65536;
    if (j < 16384) {                        // W2: K=256,F=64
        int n = j / 256, k = j - n * 256;
        w2t[j] = f2bf(W2[(size_t)k * 64 + n]);
        return;
    }
    j -= 16384;
    if (j < E) atomicAdd(&deg[ei[E + j]], 1);
}

// ---------------- CSR scan + scatter ----------------

__global__ void scan_part(const int* __restrict__ deg, int* __restrict__ offsets,
                          int* __restrict__ bsum, int N) {
    __shared__ int sh[256];
    int t = threadIdx.x;
    int base = blockIdx.x * 1024 + t * 4;
    int v0 = (base + 0 < N) ? deg[base + 0] : 0;
    int v1 = (base + 1 < N) ? deg[base + 1] : 0;
    int v2 = (base + 2 < N) ? deg[base + 2] : 0;
    int v3 = (base + 3 < N) ? deg[base + 3] : 0;
    int s = v0 + v1 + v2 + v3;
    sh[t] = s;
    __syncthreads();
    for (int off = 1; off < 256; off <<= 1) {
        int y = (t >= off) ? sh[t - off] : 0;
        __syncthreads();
        sh[t] += y;
        __syncthreads();
    }
    int p = sh[t] - s;
    if (base + 0 < N) offsets[base + 0] = p;
    p += v0;
    if (base + 1 < N) offsets[base + 1] = p;
    p += v1;
    if (base + 2 < N) offsets[base + 2] = p;
    p += v2;
    if (base + 3 < N) offsets[base + 3] = p;
    if (t == 255) bsum[blockIdx.x] = sh[255];
}

__global__ void scan_top(const int* __restrict__ bsum, int* __restrict__ bexcl,
                         int nb, int* __restrict__ offsets, int N) {
    if (threadIdx.x == 0) {
        int run = 0;
        for (int b = 0; b < nb; ++b) { bexcl[b] = run; run += bsum[b]; }
        offsets[N] = run;
    }
}

__global__ void scan_add(int* __restrict__ offsets, int* __restrict__ cursor,
                         const int* __restrict__ bexcl, int N) {
    int add = bexcl[blockIdx.x];
    int base = blockIdx.x * 1024 + threadIdx.x * 4;
#pragma unroll
    for (int k = 0; k < 4; ++k) {
        int i = base + k;
        if (i < N) { int v = offsets[i] + add; offsets[i] = v; cursor[i] = v; }
    }
}

__global__ void scatter_kernel(const int* __restrict__ ei, int* __restrict__ cursor,
                               int* __restrict__ srcs, int E) {
    int e = blockIdx.x * blockDim.x + threadIdx.x;
    if (e < E) {
        int s = ei[e];
        int d = ei[E + e];
        int p = atomicAdd(&cursor[d], 1);
        srcs[p] = s;
    }
}

// ---------------- bf16 MFMA GEMM with fused sd epilogue ----------------

typedef __attribute__((ext_vector_type(8))) short bf16x8;
typedef __attribute__((ext_vector_type(4))) float floatx4;

template <int BN, int H>
__launch_bounds__(256)
__global__ void mfma_gemm_bt(const ushort* __restrict__ A, const ushort* __restrict__ Bt,
                             ushort* __restrict__ C, const float* __restrict__ asrc,
                             const float* __restrict__ adst, float* __restrict__ sv,
                             float* __restrict__ dv, int K, int Nn) {
    constexpr int WCOLS = (BN == 128) ? 2 : 1;
    constexpr int WROWS = 4 / WCOLS;
    constexpr int MT = 128 / (WROWS * 16);
    constexpr int NT = BN / (WCOLS * 16);
    constexpr int BCALLS = (BN * 32 * 2) / 4096;

    __shared__ ushort As[128 * 32];
    __shared__ ushort Bs[BN * 32];

    int t = threadIdx.x;
    int w = t >> 6, l = t & 63;
    int row0 = blockIdx.x * 128;
    int col0 = blockIdx.y * BN;
    int wr = (w / WCOLS) * (MT * 16);
    int wc = (w % WCOLS) * (NT * 16);

    floatx4 acc[MT][NT];
#pragma unroll
    for (int mi = 0; mi < MT; ++mi)
#pragma unroll
        for (int ni = 0; ni < NT; ++ni)
#pragma unroll
            for (int r = 0; r < 4; ++r) acc[mi][ni][r] = 0.f;

    int mrow = l & 15;
    int kc = (l >> 4) * 8;

    for (int kt = 0; kt < K; kt += 32) {
#pragma unroll
        for (int c = 0; c < 2; ++c) {
            int idx = c * 256 + t;
            const ushort* gp = A + (size_t)(row0 + (idx >> 2)) * K + kt + (idx & 3) * 8;
            __builtin_amdgcn_global_load_lds(
                (const __attribute__((address_space(1))) void*)gp,
                (__attribute__((address_space(3))) void*)(As + (idx & ~63) * 8),
                16, 0, 0);
        }
#pragma unroll
        for (int c = 0; c < BCALLS; ++c) {
            int idx = c * 256 + t;
            const ushort* gp = Bt + (size_t)(col0 + (idx >> 2)) * K + kt + (idx & 3) * 8;
            __builtin_amdgcn_global_load_lds(
                (const __attribute__((address_space(1))) void*)gp,
                (__attribute__((address_space(3))) void*)(Bs + (idx & ~63) * 8),
                16, 0, 0);
        }
        __syncthreads();

        bf16x8 af[MT], bfr[NT];
#pragma unroll
        for (int mi = 0; mi < MT; ++mi)
            af[mi] = *(const bf16x8*)&As[(wr + mi * 16 + mrow) * 32 + kc];
#pragma unroll
        for (int ni = 0; ni < NT; ++ni)
            bfr[ni] = *(const bf16x8*)&Bs[(wc + ni * 16 + mrow) * 32 + kc];
#pragma unroll
        for (int mi = 0; mi < MT; ++mi)
#pragma unroll
            for (int ni = 0; ni < NT; ++ni)
                acc[mi][ni] = __builtin_amdgcn_mfma_f32_16x16x32_bf16(
                    af[mi], bfr[ni], acc[mi][ni], 0, 0, 0);
        __syncthreads();
    }

    // C store (C/D layout: col=lane&15, row=(lane>>4)*4+reg)
#pragma unroll
    for (int mi = 0; mi < MT; ++mi) {
        int rbase = row0 + wr + mi * 16 + (l >> 4) * 4;
#pragma unroll
        for (int ni = 0; ni < NT; ++ni) {
            int col = col0 + wc + ni * 16 + (l & 15);
#pragma unroll
            for (int r = 0; r < 4; ++r)
                C[(size_t)(rbase + r) * Nn + col] = f2bf(acc[mi][ni][r]);
        }
    }

    // fused sd: this wave's NT*16 cols lie in exactly one head (64 cols).
    float av[NT], bv[NT];
#pragma unroll
    for (int ni = 0; ni < NT; ++ni) {
        int ch = col0 + wc + ni * 16 + (l & 15);
        av[ni] = asrc[ch];
        bv[ni] = adst[ch];
    }
    int gh = (col0 + wc) >> 6;
#pragma unroll
    for (int mi = 0; mi < MT; ++mi) {
#pragma unroll
        for (int r = 0; r < 4; ++r) {
            float s = 0.f, d = 0.f;
#pragma unroll
            for (int ni = 0; ni < NT; ++ni) {
                float hv = acc[mi][ni][r];
                s += hv * av[ni];
                d += hv * bv[ni];
            }
#pragma unroll
            for (int m = 8; m >= 1; m >>= 1) {
                s += __shfl_xor(s, m);
                d += __shfl_xor(d, m);
            }
            if ((l & 15) == 0) {
                int row = row0 + wr + mi * 16 + (l >> 4) * 4 + r;
                sv[row * H + gh] = s;
                dv[row * H + gh] = d;
            }
        }
    }
}

// ---------------- single-pass softmax aggregation, 4-way edge-parallel ----------------
// 128 threads = 4 groups x 32 lanes. Group g handles edges beg+g, beg+g+4, ...
// Lane gl owns 8 channels [gl*8, gl*8+8) -> one uint4 (16B) load per edge.
// Cross-group combine via LDS once per node.

__launch_bounds__(128)
__global__ void agg4_kernel(const ushort* __restrict__ hb, const float* __restrict__ sv,
                            const float* __restrict__ dv, const int* __restrict__ offsets,
                            const int* __restrict__ srcs, const float* __restrict__ bias,
                            ushort* __restrict__ zb, int N) {
    __shared__ float lsum[4][256];
    __shared__ float lden[4][4];

    int i = blockIdx.x;
    int t = threadIdx.x;
    int grp = t >> 5, gl = t & 31;
    int head = gl >> 3;                 // head of this lane's channels
    int beg = offsets[i], end = offsets[i + 1];

    float d_i = dv[i * 4 + head];
    float ax[8] = {};
    float den = 0.f;

    int j = beg + grp;
    int srcn = (j < end) ? srcs[j] : 0;
    while (j < end) {
        float sval = sv[srcn * 4 + head];
        uint4 q = *(const uint4*)&hb[(size_t)srcn * 256 + gl * 8];
        int jn = j + 4;
        int srcn_n = (jn < end) ? srcs[jn] : 0;
        float wgt = __expf(fminf(lrelu(sval + d_i), 60.f));
        den += wgt;
        uint pr[4] = {q.x, q.y, q.z, q.w};
#pragma unroll
        for (int k = 0; k < 4; ++k) {
            ax[2 * k]     += wgt * bf2f(pr[k] & 0xffffu);
            ax[2 * k + 1] += wgt * bf2f(pr[k] >> 16);
        }
        j = jn; srcn = srcn_n;
    }

#pragma unroll
    for (int k = 0; k < 8; ++k) lsum[grp][gl * 8 + k] = ax[k];
    if ((gl & 7) == 0) lden[grp][head] = den;
    __syncthreads();

    // final: thread t owns channels {2t, 2t+1}; head = t>>5
    int h = t >> 5;
    float wself = __expf(fminf(lrelu(sv[i * 4 + h] + dv[i * 4 + h]), 60.f));
    float dtot = lden[0][h] + lden[1][h] + lden[2][h] + lden[3][h] + wself + 1e-16f;
    float rden = 1.f / dtot;
    uint p = *(const uint*)&hb[(size_t)i * 256 + 2 * t];
    float a0 = lsum[0][2 * t] + lsum[1][2 * t] + lsum[2][2 * t] + lsum[3][2 * t]
             + wself * bf2f(p & 0xffffu);
    float a1 = lsum[0][2 * t + 1] + lsum[1][2 * t + 1] + lsum[2][2 * t + 1]
             + lsum[3][2 * t + 1] + wself * bf2f(p >> 16);
    a0 = a0 * rden + bias[2 * t];
    a1 = a1 * rden + bias[2 * t + 1];
    *(uint*)&zb[(size_t)i * 256 + 2 * t] = (uint)f2bf(a0) | ((uint)f2bf(a1) << 16);
}

// H=1, 64 channels: 64 threads = 4 groups x 16 lanes, uint2 (4ch) per lane,
// cross-group combine via in-wave shuffles.

__launch_bounds__(64)
__global__ void agg1_kernel(const ushort* __restrict__ hb, const float* __restrict__ sv,
                            const float* __restrict__ dv, const int* __restrict__ offsets,
                            const int* __restrict__ srcs, const float* __restrict__ bias,
                            ushort* __restrict__ zb, int N) {
    int i = blockIdx.x;
    int l = threadIdx.x;
    int grp = l >> 4, gl = l & 15;
    int beg = offsets[i], end = offsets[i + 1];

    float d_i = dv[i];
    float ax[4] = {};
    float den = 0.f;

    int j = beg + grp;
    int srcn = (j < end) ? srcs[j] : 0;
    while (j < end) {
        float sval = sv[srcn];
        uint2 q = *(const uint2*)&hb[(size_t)srcn * 64 + gl * 4];
        int jn = j + 4;
        int srcn_n = (jn < end) ? srcs[jn] : 0;
        float wgt = __expf(fminf(lrelu(sval + d_i), 60.f));
        den += wgt;
        ax[0] += wgt * bf2f(q.x & 0xffffu);
        ax[1] += wgt * bf2f(q.x >> 16);
        ax[2] += wgt * bf2f(q.y & 0xffffu);
        ax[3] += wgt * bf2f(q.y >> 16);
        j = jn; srcn = srcn_n;
    }

    // combine the 4 groups (lanes l, l^16, l^32, l^48)
#pragma unroll
    for (int k = 0; k < 4; ++k) {
        ax[k] += __shfl_xor(ax[k], 16);
        ax[k] += __shfl_xor(ax[k], 32);
    }
    den += __shfl_xor(den, 16);
    den += __shfl_xor(den, 32);

    if (l < 16) {
        float wself = __expf(fminf(lrelu(sv[i] + d_i), 60.f));
        float rden = 1.f / (den + wself + 1e-16f);
        uint2 q = *(const uint2*)&hb[(size_t)i * 64 + gl * 4];
        float a0 = (ax[0] + wself * bf2f(q.x & 0xffffu)) * rden + bias[gl * 4 + 0];
        float a1 = (ax[1] + wself * bf2f(q.x >> 16)) * rden + bias[gl * 4 + 1];
        float a2 = (ax[2] + wself * bf2f(q.y & 0xffffu)) * rden + bias[gl * 4 + 2];
        float a3 = (ax[3] + wself * bf2f(q.y >> 16)) * rden + bias[gl * 4 + 3];
        uint2 o;
        o.x = (uint)f2bf(a0) | ((uint)f2bf(a1) << 16);
        o.y = (uint)f2bf(a2) | ((uint)f2bf(a3) << 16);
        *(uint2*)&zb[(size_t)i * 64 + gl * 4] = o;
    }
}

// ---------------- BatchNorm stats: vectorized grid-stride partials ----------------

template <int F>
__launch_bounds__(256)
__global__ void bn_stats_kernel(const ushort* __restrict__ x, float* __restrict__ ps,
                                float* __restrict__ pq, int N) {
    constexpr int OCT = F / 8;
    __shared__ float lds_s[F], lds_q[F];
    int t = threadIdx.x;
    if (t < F) { lds_s[t] = 0.f; lds_q[t] = 0.f; }
    __syncthreads();

    float s[8] = {}, q[8] = {};
    int total8 = N * F / 8;
    for (int idx = blockIdx.x * 256 + t; idx < total8; idx += NB_RED * 256) {
        uint4 v = ((const uint4*)x)[idx];
        uint pr[4] = {v.x, v.y, v.z, v.w};
#pragma unroll
        for (int k = 0; k < 4; ++k) {
            float a = bf2f(pr[k] & 0xffffu);
            float b = bf2f(pr[k] >> 16);
            s[2 * k] += a;     q[2 * k] += a * a;
            s[2 * k + 1] += b; q[2 * k + 1] += b * b;
        }
    }
    int co = t % OCT;
#pragma unroll
    for (int j = 0; j < 8; ++j) {
        atomicAdd(&lds_s[co * 8 + j], s[j]);
        atomicAdd(&lds_q[co * 8 + j], q[j]);
    }
    __syncthreads();
    if (t < F) {
        ps[blockIdx.x * F + t] = lds_s[t];
        pq[blockIdx.x * F + t] = lds_q[t];
    }
}

__global__ void bn_final_kernel(const float* __restrict__ ps, const float* __restrict__ pq,
                                const float* __restrict__ g, const float* __restrict__ be,
                                float* __restrict__ scale, float* __restrict__ shift,
                                int N, int F) {
    int t = threadIdx.x;
    if (t < F) {
        float s = 0.f, q = 0.f;
        for (int b = 0; b < NB_RED; ++b) { s += ps[b * F + t]; q += pq[b * F + t]; }
        float mean = s / (float)N;
        float var = q / (float)N - mean * mean;
        float sc = g[t] * rsqrtf(var + BN_EPS);
        scale[t] = sc;
        shift[t] = be[t] - sc * mean;
    }
}

__global__ void bn_apply_kernel(uint* __restrict__ x, const float* __restrict__ scale,
                                const float* __restrict__ shift, int totalPairs, int Fmask) {
    int i = blockIdx.x * blockDim.x + threadIdx.x;
    if (i < totalPairs) {
        uint p = x[i];
        int c0 = (2 * i) & Fmask;
        float v0 = fmaxf(bf2f(p & 0xffffu) * scale[c0] + shift[c0], 0.f);
        float v1 = fmaxf(bf2f(p >> 16) * scale[c0 + 1] + shift[c0 + 1], 0.f);
        x[i] = (uint)f2bf(v0) | ((uint)f2bf(v1) << 16);
    }
}

// ---------------- pooling (BN+ReLU fused, vectorized) ----------------

__launch_bounds__(256)
__global__ void pool_kernel(const ushort* __restrict__ y, const float* __restrict__ scale,
                            const float* __restrict__ shift, float* __restrict__ psum,
                            float* __restrict__ pmax, int N) {
    constexpr int F = 64, OCT = 8;
    __shared__ float lds_s[F];
    __shared__ uint lds_m[F];
    int t = threadIdx.x;
    if (t < F) { lds_s[t] = 0.f; lds_m[t] = 0u; }
    __syncthreads();

    int co = t % OCT;
    float sc[8], sh[8];
#pragma unroll
    for (int j = 0; j < 8; ++j) { sc[j] = scale[co * 8 + j]; sh[j] = shift[co * 8 + j]; }

    float s[8] = {}, m[8] = {};
    int total8 = N * F / 8;
    for (int idx = blockIdx.x * 256 + t; idx < total8; idx += NB_RED * 256) {
        uint4 v = ((const uint4*)y)[idx];
        uint pr[4] = {v.x, v.y, v.z, v.w};
#pragma unroll
        for (int k = 0; k < 4; ++k) {
            float a = fmaxf(bf2f(pr[k] & 0xffffu) * sc[2 * k] + sh[2 * k], 0.f);
            float b = fmaxf(bf2f(pr[k] >> 16) * sc[2 * k + 1] + sh[2 * k + 1], 0.f);
            s[2 * k] += a;     m[2 * k] = fmaxf(m[2 * k], a);
            s[2 * k + 1] += b; m[2 * k + 1] = fmaxf(m[2 * k + 1], b);
        }
    }
#pragma unroll
    for (int j = 0; j < 8; ++j) {
        atomicAdd(&lds_s[co * 8 + j], s[j]);
        atomicMax(&lds_m[co * 8 + j], __float_as_uint(m[j]));
    }
    __syncthreads();
    if (t < F) {
        psum[blockIdx.x * F + t] = lds_s[t];
        pmax[blockIdx.x * F + t] = __uint_as_float(lds_m[t]);
    }
}

__global__ void classify_kernel(const float* __restrict__ psum, const float* __restrict__ pmax,
                                const float* __restrict__ Wc1, const float* __restrict__ bc1,
                                const float* __restrict__ Wc2, const float* __restrict__ bc2,
                                float* __restrict__ out, int N) {
    __shared__ float pooled[128];
    __shared__ float z[64];
    int t = threadIdx.x;   // 128 threads
    if (t < 64) {
        float s = 0.f;
        for (int b = 0; b < NB_RED; ++b) s += psum[b * 64 + t];
        pooled[t] = s / (float)N;
    } else {
        int c = t - 64;
        float m = 0.f;
        for (int b = 0; b < NB_RED; ++b) m = fmaxf(m, pmax[b * 64 + c]);
        pooled[t] = m;
    }
    __syncthreads();
    if (t < 64) {
        float a = bc1[t];
        for (int k = 0; k < 128; ++k) a += pooled[k] * Wc1[k * 64 + t];
        z[t] = a > 0.f ? a : 0.f;
    }
    __syncthreads();
    if (t < 2) {
        float a = bc2[t];
        for (int j = 0; j < 64; ++j) a += z[j] * Wc2[j * 2 + t];
        out[t] = a;
    }
}

// ---------------- driver ----------------

extern "C" void kernel_launch(void* const* d_in, const int* in_sizes, int n_in,
                              void* d_out, int out_size, void* d_ws, size_t ws_size,
                              hipStream_t stream) {
    const float* x   = (const float*)d_in[0];
    const int*   ei  = (const int*)d_in[1];
    const float* W0  = (const float*)d_in[2];  const float* b0  = (const float*)d_in[3];
    const float* as0 = (const float*)d_in[4];  const float* ad0 = (const float*)d_in[5];
    const float* g0  = (const float*)d_in[6];  const float* be0 = (const float*)d_in[7];
    const float* W1  = (const float*)d_in[8];  const float* b1  = (const float*)d_in[9];
    const float* as1 = (const float*)d_in[10]; const float* ad1 = (const float*)d_in[11];
    const float* g1  = (const float*)d_in[12]; const float* be1 = (const float*)d_in[13];
    const float* W2  = (const float*)d_in[14]; const float* b2  = (const float*)d_in[15];
    const float* as2 = (const float*)d_in[16]; const float* ad2 = (const float*)d_in[17];
    const float* g2  = (const float*)d_in[18]; const float* be2 = (const float*)d_in[19];
    const float* Wc1 = (const float*)d_in[20]; const float* bc1 = (const float*)d_in[21];
    const float* Wc2 = (const float*)d_in[22]; const float* bc2 = (const float*)d_in[23];
    float* out = (float*)d_out;

    const int N = in_sizes[0] / 128;            // 50000
    const int E = in_sizes[1] / 2;              // 800000
    const int Mpad = ((N + 127) / 128) * 128;   // 50048
    const int NB_SCAN = (N + 1023) / 1024;      // 49

    char* ws = (char*)d_ws;
    size_t o = 0;
    auto alloc = [&](size_t bytes) -> void* {
        void* p = ws + o;
        o = (o + bytes + 255) & ~(size_t)255;
        return p;
    };
    int*    deg     = (int*)alloc((size_t)N * 4);
    int*    offsets = (int*)alloc((size_t)(N + 1) * 4);
    int*    cursor  = (int*)alloc((size_t)N * 4);
    int*    srcs    = (int*)alloc((size_t)E * 4);
    int*    bsum    = (int*)alloc((size_t)NB_SCAN * 4);
    int*    bexcl   = (int*)alloc((size_t)NB_SCAN * 4);
    ushort* xb      = (ushort*)alloc((size_t)Mpad * 128 * 2);
    ushort* w0t     = (ushort*)alloc((size_t)256 * 128 * 2);
    ushort* w1t     = (ushort*)alloc((size_t)256 * 256 * 2);
    ushort* w2t     = (ushort*)alloc((size_t)64 * 256 * 2);
    ushort* hb      = (ushort*)alloc((size_t)Mpad * 256 * 2);
    ushort* zb      = (ushort*)alloc((size_t)Mpad * 256 * 2);
    float*  sv      = (float*)alloc((size_t)Mpad * 4 * 4);
    float*  dv      = (float*)alloc((size_t)Mpad * 4 * 4);
    float*  ps      = (float*)alloc((size_t)NB_RED * 256 * 4);
    float*  pq      = (float*)alloc((size_t)NB_RED * 256 * 4);
    float*  scale   = (float*)alloc(256 * 4);
    float*  shift   = (float*)alloc(256 * 4);
    float*  psum    = (float*)alloc((size_t)NB_RED * 64 * 4);
    float*  pmax    = (float*)alloc((size_t)NB_RED * 64 * 4);

    // ---- prep (cvt + transpose + histogram) ----
    hipMemsetAsync(deg, 0, (size_t)N * 4, stream);
    int prep_total = Mpad * 128 + 32768 + 65536 + 16384 + E;
    prep_kernel<<<(prep_total + 255) / 256, 256, 0, stream>>>(
        x, xb, N * 128, Mpad * 128, W0, w0t, W1, w1t, W2, w2t, ei, deg, E);

    // ---- CSR scan + scatter ----
    scan_part<<<NB_SCAN, 256, 0, stream>>>(deg, offsets, bsum, N);
    scan_top<<<1, 64, 0, stream>>>(bsum, bexcl, NB_SCAN, offsets, N);
    scan_add<<<NB_SCAN, 256, 0, stream>>>(offsets, cursor, bexcl, N);
    scatter_kernel<<<(E + 255) / 256, 256, 0, stream>>>(ei, cursor, srcs, E);

    // ---- layer 0 ----
    {
        dim3 gg(Mpad / 128, 2);
        mfma_gemm_bt<128, 4><<<gg, 256, 0, stream>>>(xb, w0t, hb, as0, ad0, sv, dv, 128, 256);
        agg4_kernel<<<N, 128, 0, stream>>>(hb, sv, dv, offsets, srcs, b0, zb, N);
        bn_stats_kernel<256><<<NB_RED, 256, 0, stream>>>(zb, ps, pq, N);
        bn_final_kernel<<<1, 256, 0, stream>>>(ps, pq, g0, be0, scale, shift, N, 256);
        bn_apply_kernel<<<(N * 128 + 255) / 256, 256, 0, stream>>>((uint*)zb, scale, shift,
                                                                   N * 128, 255);
    }
    // ---- layer 1 ----
    {
        dim3 gg(Mpad / 128, 2);
        mfma_gemm_bt<128, 4><<<gg, 256, 0, stream>>>(zb, w1t, hb, as1, ad1, sv, dv, 256, 256);
        agg4_kernel<<<N, 128, 0, stream>>>(hb, sv, dv, offsets, srcs, b1, zb, N);
        bn_stats_kernel<256><<<NB_RED, 256, 0, stream>>>(zb, ps, pq, N);
        bn_final_kernel<<<1, 256, 0, stream>>>(ps, pq, g1, be1, scale, shift, N, 256);
        bn_apply_kernel<<<(N * 128 + 255) / 256, 256, 0, stream>>>((uint*)zb, scale, shift,
                                                                   N * 128, 255);
    }
    // ---- layer 2 (1 head, F=64); BN-apply fused into pool ----
    {
        dim3 gg(Mpad / 128, 1);
        mfma_gemm_bt<64, 1><<<gg, 256, 0, stream>>>(zb, w2t, hb, as2, ad2, sv, dv, 256, 64);
        agg1_kernel<<<N, 64, 0, stream>>>(hb, sv, dv, offsets, srcs, b2, zb, N);
        bn_stats_kernel<64><<<NB_RED, 256, 0, stream>>>(zb, ps, pq, N);
        bn_final_kernel<<<1, 64, 0, stream>>>(ps, pq, g2, be2, scale, shift, N, 64);
    }

    // ---- pooling (BN+ReLU fused) + classifier ----
    pool_kernel<<<NB_RED, 256, 0, stream>>>(zb, scale, shift, psum, pmax, N);
    classify_kernel<<<1, 128, 0, stream>>>(psum, pmax, Wc1, bc1, Wc2, bc2, out, N);
}